// Round 9
// baseline (115.518 us; speedup 1.0000x reference)
//
#include <hip/hip_runtime.h>

typedef _Float16 half_t;
typedef _Float16 half8_t __attribute__((ext_vector_type(8)));
typedef float    f32x4  __attribute__((ext_vector_type(4)));

// Problem constants (from reference)
constexpr int BB  = 4;
constexpr int CC  = 128;
constexpr int HWW = 16384;     // H*W
constexpr int NV  = 32;        // votes per sphere point
constexpr int NP  = 4096;      // points per batch
constexpr int PT  = 16;        // points per gather block (16 sg x 8 lanes)

// R9 = MEASUREMENT ROUND: kernels identical to R8; kernel_launch launches
// transpose x2 and gather x2 (both idempotent -> output identical).
// dur_R9 - dur_R8 = T + G + 2 launch gaps = true controllable kernel cost,
// invisible to rocprof top-5 (harness poison-fills dominate the table).

// ---------------------------------------------------------------------------
// Kernel 1: transpose+convert x [B][C][HW] fp32 -> xt [B][HW][C] fp16.
// 1D grid, 2048 blocks: q=bid&7 -> (b=q>>1, c-half h=q&1); t=bid>>3 -> hw0.
// XCD q owns xt slice (b, h) = 2 MB < 4 MB per-XCD L2; gather uses the SAME
// mapping so the writing XCD is the reading XCD (R7: -13.6 us).
// ---------------------------------------------------------------------------
__global__ __launch_bounds__(256) void transpose_h(const float* __restrict__ x,
                                                   half_t* __restrict__ xt) {
  __shared__ float tile[64][65];
  const int bid = blockIdx.x;
  const int q   = bid & 7;
  const int b   = q >> 1;
  const int c0  = (q & 1) * 64;
  const int hw0 = (bid >> 3) * 64;
  const int tid = threadIdx.x;
  const float* xb = x + (size_t)b * CC * HWW;

  const int hw4 = (tid & 15) * 4;
  const int cr  = tid >> 4;          // 0..15
#pragma unroll
  for (int j = 0; j < 4; ++j) {
    const int c = cr + j * 16;       // 0..63
    const f32x4 v = __builtin_nontemporal_load(
        reinterpret_cast<const f32x4*>(xb + (size_t)(c0 + c) * HWW + hw0 + hw4));
    tile[c][hw4 + 0] = v.x;
    tile[c][hw4 + 1] = v.y;
    tile[c][hw4 + 2] = v.z;
    tile[c][hw4 + 3] = v.w;
  }
  __syncthreads();

  half_t* xtb = xt + (size_t)b * HWW * CC;
  const int c8 = (tid & 7) * 8;      // 0..56 (64 channels in tile)
  const int hr = tid >> 3;           // 0..31
#pragma unroll
  for (int j = 0; j < 2; ++j) {
    const int hwr = hr + j * 32;     // 0..63
    half8_t hv;
#pragma unroll
    for (int k = 0; k < 8; ++k) hv[k] = (half_t)tile[c8 + k][hwr];
    *reinterpret_cast<half8_t*>(xtb + (size_t)(hw0 + hwr) * CC + c0 + c8) = hv;
  }
}

// ---------------------------------------------------------------------------
// Kernel 2: gather + weighted vote accumulation, L2-resident per XCD.
// 1D grid, 2048 blocks: q=bid&7 -> (b, c-half h); chunk=bid>>3 -> p0.
// 128 threads = 16 subgroups of 8 lanes; sg owns point p0+sg; lane c8 owns
// channels 64h+8*c8..+7 (one 16B half8 per vote; 32 independent loads).
// fp32 accumulation. Output restaged via LDS -> plain f32x4 stores.
// ---------------------------------------------------------------------------
__global__ __launch_bounds__(128, 4) void gather_h(const half_t* __restrict__ xt,
                                                   const int* __restrict__ vote_index,
                                                   const float* __restrict__ vote_weight,
                                                   const int* __restrict__ inds,
                                                   float* __restrict__ out) {
  const int bid = blockIdx.x;
  const int q   = bid & 7;
  const int b   = q >> 1;
  const int h   = q & 1;
  const int p0  = (bid >> 3) * PT;
  const int tid = threadIdx.x;
  const int sg  = tid >> 3;   // 0..15 point
  const int c8  = tid & 7;    // channel octet within this half

  __shared__ int   s_idx[PT][NV];
  __shared__ float s_w[PT][NV];
#pragma unroll
  for (int i = tid; i < PT * NV; i += 128) {
    const int pp = i >> 5;    // NV == 32
    const int v  = i & (NV - 1);
    const int s  = inds[b * NP + p0 + pp];
    s_idx[pp][v] = vote_index[s * NV + v] * CC;   // row offset in half units
    s_w[pp][v]   = vote_weight[s * NV + v];
  }
  __syncthreads();

  const half_t* xb = xt + (size_t)b * HWW * CC + h * 64 + c8 * 8;

  float acc[8] = {0.f, 0.f, 0.f, 0.f, 0.f, 0.f, 0.f, 0.f};
#pragma unroll
  for (int v = 0; v < NV; ++v) {
    const half8_t xv = *reinterpret_cast<const half8_t*>(xb + s_idx[sg][v]);
    const float   w  = s_w[sg][v];
#pragma unroll
    for (int k = 0; k < 8; ++k) acc[k] += (float)xv[k] * w;
  }
  __syncthreads();

  // Restage: s_out[64 local channels][PT+4 pad].
  __shared__ float s_out[64][PT + 4];
#pragma unroll
  for (int k = 0; k < 8; ++k) s_out[c8 * 8 + k][sg] = acc[k];
  __syncthreads();

  // Thread t: local channel t>>1, point-octet t&1 -> two plain f32x4 stores.
  const int cloc = tid >> 1;
  const int ph   = (tid & 1) * 8;
  float* ob = out + ((size_t)b * CC + 64 * h + cloc) * NP + p0 + ph;
  const f32x4 o0 = {s_out[cloc][ph + 0], s_out[cloc][ph + 1],
                    s_out[cloc][ph + 2], s_out[cloc][ph + 3]};
  const f32x4 o1 = {s_out[cloc][ph + 4], s_out[cloc][ph + 5],
                    s_out[cloc][ph + 6], s_out[cloc][ph + 7]};
  *reinterpret_cast<f32x4*>(ob)     = o0;
  *reinterpret_cast<f32x4*>(ob + 4) = o1;
}

// ---------------------------------------------------------------------------
// Fallback (no workspace): direct fp32 gather, correct but uncoalesced.
// ---------------------------------------------------------------------------
__global__ __launch_bounds__(128) void gather_fallback_k(const float* __restrict__ x,
                                                         const int* __restrict__ vote_index,
                                                         const float* __restrict__ vote_weight,
                                                         const int* __restrict__ inds,
                                                         float* __restrict__ out) {
  const int b = blockIdx.y;
  const int p = blockIdx.x;
  const int c = threadIdx.x;
  const int s = inds[b * NP + p];
  const float* xb = x + ((size_t)b * CC + c) * HWW;
  float a = 0.f;
  for (int v = 0; v < NV; ++v)
    a += xb[vote_index[s * NV + v]] * vote_weight[s * NV + v];
  out[((size_t)b * CC + c) * NP + p] = a;
}

// ---------------------------------------------------------------------------
extern "C" void kernel_launch(void* const* d_in, const int* in_sizes, int n_in,
                              void* d_out, int out_size, void* d_ws, size_t ws_size,
                              hipStream_t stream) {
  const float* x           = (const float*)d_in[0];
  const int*   vote_index  = (const int*)d_in[1];
  const float* vote_weight = (const float*)d_in[2];
  const int*   inds        = (const int*)d_in[3];
  float*       out         = (float*)d_out;

  const size_t xt_bytes = (size_t)BB * HWW * CC * sizeof(half_t);  // 16 MB
  if (ws_size >= xt_bytes) {
    half_t* xt = (half_t*)d_ws;
    // MEASUREMENT: each kernel launched twice (idempotent). Delta vs the
    // single-launch round = T + G + 2 gaps = controllable kernel cost.
    transpose_h<<<2048, 256, 0, stream>>>(x, xt);
    transpose_h<<<2048, 256, 0, stream>>>(x, xt);
    gather_h<<<2048, 128, 0, stream>>>(xt, vote_index, vote_weight, inds, out);
    gather_h<<<2048, 128, 0, stream>>>(xt, vote_index, vote_weight, inds, out);
  } else {
    dim3 gg(NP, BB);
    gather_fallback_k<<<gg, CC, 0, stream>>>(x, vote_index, vote_weight, inds, out);
  }
}

// Round 10
// 97.377 us; speedup vs baseline: 1.1863x; 1.1863x over previous
//
#include <hip/hip_runtime.h>

typedef _Float16 half_t;
typedef _Float16 half8_t __attribute__((ext_vector_type(8)));
typedef float    f32x4  __attribute__((ext_vector_type(4)));

// Problem constants (from reference)
constexpr int BB  = 4;
constexpr int CC  = 128;
constexpr int HWW = 16384;     // H*W
constexpr int NV  = 32;        // votes per sphere point
constexpr int NP  = 4096;      // points per batch
constexpr int PT  = 16;        // points per gather block (16 sg x 8 lanes)

// FINAL (R10): single launches, kernels identical to R8 (98.0/98.3 us).
// R9 double-launch probe measured T+G+2gaps = 17.2 us vs ~14 us arithmetic
// floor (transpose 50 MB HBM ~8 us; gather 134 MB L2-resident ~5-6 us) ->
// kernels are at ~90% of their memory floor. Total dur is dominated by
// ~82 us of fixed harness poison-fill/restore traffic (268 MB ws + out +
// 37 MB inputs) that kernel code cannot affect.
//
// Structure: (1) transpose+fp16-convert x [B][C][HW] -> xt [B][HW][C], so a
// vote's 128 channels are one contiguous 256B row; (2) XCD-aware mapping
// (bid&7 -> batch x channel-half) makes each XCD's 2 MB xt slice L2-resident
// (R7: -13.6 us); (3) fp16 halves gather traffic (R4: -18 us; absmax 0.125
// well under 0.36 threshold).

// ---------------------------------------------------------------------------
// Kernel 1: transpose+convert x [B][C][HW] fp32 -> xt [B][HW][C] fp16.
// 1D grid, 2048 blocks: q=bid&7 -> (b=q>>1, c-half h=q&1); t=bid>>3 -> hw0.
// Phase 1: f32x4 nontemporal reads (x read-once; keep L2 for xt).
// Phase 2: half8 (16B) plain stores into this XCD's xt slice.
// ---------------------------------------------------------------------------
__global__ __launch_bounds__(256) void transpose_h(const float* __restrict__ x,
                                                   half_t* __restrict__ xt) {
  __shared__ float tile[64][65];
  const int bid = blockIdx.x;
  const int q   = bid & 7;
  const int b   = q >> 1;
  const int c0  = (q & 1) * 64;
  const int hw0 = (bid >> 3) * 64;
  const int tid = threadIdx.x;
  const float* xb = x + (size_t)b * CC * HWW;

  const int hw4 = (tid & 15) * 4;
  const int cr  = tid >> 4;          // 0..15
#pragma unroll
  for (int j = 0; j < 4; ++j) {
    const int c = cr + j * 16;       // 0..63
    const f32x4 v = __builtin_nontemporal_load(
        reinterpret_cast<const f32x4*>(xb + (size_t)(c0 + c) * HWW + hw0 + hw4));
    tile[c][hw4 + 0] = v.x;
    tile[c][hw4 + 1] = v.y;
    tile[c][hw4 + 2] = v.z;
    tile[c][hw4 + 3] = v.w;
  }
  __syncthreads();

  half_t* xtb = xt + (size_t)b * HWW * CC;
  const int c8 = (tid & 7) * 8;      // 0..56 (64 channels in tile)
  const int hr = tid >> 3;           // 0..31
#pragma unroll
  for (int j = 0; j < 2; ++j) {
    const int hwr = hr + j * 32;     // 0..63
    half8_t hv;
#pragma unroll
    for (int k = 0; k < 8; ++k) hv[k] = (half_t)tile[c8 + k][hwr];
    *reinterpret_cast<half8_t*>(xtb + (size_t)(hw0 + hwr) * CC + c0 + c8) = hv;
  }
}

// ---------------------------------------------------------------------------
// Kernel 2: gather + weighted vote accumulation, L2-resident per XCD.
// 1D grid, 2048 blocks: q=bid&7 -> (b, c-half h); chunk=bid>>3 -> p0.
// 128 threads = 16 subgroups of 8 lanes; sg owns point p0+sg; lane c8 owns
// channels 64h+8*c8..+7 (one 16B half8 per vote; 32 independent loads =
// full MLP). fp32 accumulation. Output restaged via LDS -> plain f32x4
// stores (L2 merges neighbor chunks into full-line writebacks).
// ---------------------------------------------------------------------------
__global__ __launch_bounds__(128, 4) void gather_h(const half_t* __restrict__ xt,
                                                   const int* __restrict__ vote_index,
                                                   const float* __restrict__ vote_weight,
                                                   const int* __restrict__ inds,
                                                   float* __restrict__ out) {
  const int bid = blockIdx.x;
  const int q   = bid & 7;
  const int b   = q >> 1;
  const int h   = q & 1;
  const int p0  = (bid >> 3) * PT;
  const int tid = threadIdx.x;
  const int sg  = tid >> 3;   // 0..15 point
  const int c8  = tid & 7;    // channel octet within this half

  __shared__ int   s_idx[PT][NV];
  __shared__ float s_w[PT][NV];
#pragma unroll
  for (int i = tid; i < PT * NV; i += 128) {
    const int pp = i >> 5;    // NV == 32
    const int v  = i & (NV - 1);
    const int s  = inds[b * NP + p0 + pp];
    s_idx[pp][v] = vote_index[s * NV + v] * CC;   // row offset in half units
    s_w[pp][v]   = vote_weight[s * NV + v];
  }
  __syncthreads();

  const half_t* xb = xt + (size_t)b * HWW * CC + h * 64 + c8 * 8;

  float acc[8] = {0.f, 0.f, 0.f, 0.f, 0.f, 0.f, 0.f, 0.f};
#pragma unroll
  for (int v = 0; v < NV; ++v) {
    const half8_t xv = *reinterpret_cast<const half8_t*>(xb + s_idx[sg][v]);
    const float   w  = s_w[sg][v];
#pragma unroll
    for (int k = 0; k < 8; ++k) acc[k] += (float)xv[k] * w;
  }
  __syncthreads();

  // Restage: s_out[64 local channels][PT+4 pad].
  __shared__ float s_out[64][PT + 4];
#pragma unroll
  for (int k = 0; k < 8; ++k) s_out[c8 * 8 + k][sg] = acc[k];
  __syncthreads();

  // Thread t: local channel t>>1, point-octet t&1 -> two plain f32x4 stores.
  const int cloc = tid >> 1;
  const int ph   = (tid & 1) * 8;
  float* ob = out + ((size_t)b * CC + 64 * h + cloc) * NP + p0 + ph;
  const f32x4 o0 = {s_out[cloc][ph + 0], s_out[cloc][ph + 1],
                    s_out[cloc][ph + 2], s_out[cloc][ph + 3]};
  const f32x4 o1 = {s_out[cloc][ph + 4], s_out[cloc][ph + 5],
                    s_out[cloc][ph + 6], s_out[cloc][ph + 7]};
  *reinterpret_cast<f32x4*>(ob)     = o0;
  *reinterpret_cast<f32x4*>(ob + 4) = o1;
}

// ---------------------------------------------------------------------------
// Fallback (no workspace): direct fp32 gather, correct but uncoalesced.
// ---------------------------------------------------------------------------
__global__ __launch_bounds__(128) void gather_fallback_k(const float* __restrict__ x,
                                                         const int* __restrict__ vote_index,
                                                         const float* __restrict__ vote_weight,
                                                         const int* __restrict__ inds,
                                                         float* __restrict__ out) {
  const int b = blockIdx.y;
  const int p = blockIdx.x;
  const int c = threadIdx.x;
  const int s = inds[b * NP + p];
  const float* xb = x + ((size_t)b * CC + c) * HWW;
  float a = 0.f;
  for (int v = 0; v < NV; ++v)
    a += xb[vote_index[s * NV + v]] * vote_weight[s * NV + v];
  out[((size_t)b * CC + c) * NP + p] = a;
}

// ---------------------------------------------------------------------------
extern "C" void kernel_launch(void* const* d_in, const int* in_sizes, int n_in,
                              void* d_out, int out_size, void* d_ws, size_t ws_size,
                              hipStream_t stream) {
  const float* x           = (const float*)d_in[0];
  const int*   vote_index  = (const int*)d_in[1];
  const float* vote_weight = (const float*)d_in[2];
  const int*   inds        = (const int*)d_in[3];
  float*       out         = (float*)d_out;

  const size_t xt_bytes = (size_t)BB * HWW * CC * sizeof(half_t);  // 16 MB
  if (ws_size >= xt_bytes) {
    half_t* xt = (half_t*)d_ws;
    transpose_h<<<2048, 256, 0, stream>>>(x, xt);
    gather_h<<<2048, 128, 0, stream>>>(xt, vote_index, vote_weight, inds, out);
  } else {
    dim3 gg(NP, BB);
    gather_fallback_k<<<gg, CC, 0, stream>>>(x, vote_index, vote_weight, inds, out);
  }
}